// Round 1
// baseline (514.605 us; speedup 1.0000x reference)
//
#include <hip/hip_runtime.h>
#include <hip/hip_bf16.h>

#define B_  2
#define T_  2048
#define D_  2048
#define H_  16
#define HD_ 128
#define NT_ 4096   // B*T
#define D3_ 6144   // 3*D

typedef __bf16 bf16;
typedef bf16 bf16x2 __attribute__((ext_vector_type(2)));
typedef bf16 bf16x4 __attribute__((ext_vector_type(4)));
typedef bf16 bf16x8 __attribute__((ext_vector_type(8)));
typedef float floatx4 __attribute__((ext_vector_type(4)));

__device__ __forceinline__ void gl_lds16(const bf16* g, bf16* l) {
    __builtin_amdgcn_global_load_lds((const __attribute__((address_space(1))) void*)g,
                                     (__attribute__((address_space(3))) void*)l, 16, 0, 0);
}

// ---------------- fp32 -> bf16 elementwise ----------------
__global__ __launch_bounds__(256) void k_cvt(const float* __restrict__ in, bf16* __restrict__ out, int n4) {
    int i = blockIdx.x * 256 + threadIdx.x;
    if (i >= n4) return;
    float4 v = ((const float4*)in)[i];
    bf16x4 o = { (bf16)v.x, (bf16)v.y, (bf16)v.z, (bf16)v.w };
    ((bf16x4*)out)[i] = o;
}

// ---------------- fp32 (RxC) -> bf16 transposed (CxR) ----------------
__global__ __launch_bounds__(256) void k_tcvt(const float* __restrict__ in, bf16* __restrict__ out, int R, int C) {
    __shared__ float tile[64][65];
    int c0 = blockIdx.x * 64, r0 = blockIdx.y * 64;
    int tid = threadIdx.x;
#pragma unroll
    for (int i = 0; i < 16; i++) {
        int idx = tid + i * 256, r = idx >> 6, c = idx & 63;
        tile[r][c] = in[(size_t)(r0 + r) * C + (c0 + c)];
    }
    __syncthreads();
#pragma unroll
    for (int i = 0; i < 16; i++) {
        int idx = tid + i * 256, r = idx >> 6, c = idx & 63;
        out[(size_t)(c0 + r) * R + (r0 + c)] = (bf16)tile[c][r];
    }
}

// ---------------- bf16 GEMM: C[MxN] = A[MxK] * Bt[NxK]^T ----------------
template <typename OutT>
__global__ __launch_bounds__(256) void k_gemm_bt(const bf16* __restrict__ A, const bf16* __restrict__ Bt,
                                                 OutT* __restrict__ C, int M, int N, int K) {
    __shared__ bf16 As[128 * 32];
    __shared__ bf16 Bs[128 * 32];
    const int tid = threadIdx.x, w = tid >> 6, lane = tid & 63;
    const int quad = lane >> 4, l16 = lane & 15;
    const int n0 = blockIdx.x * 128, m0 = blockIdx.y * 128;
    const int wr = (w >> 1) * 64, wc = (w & 1) * 64;
    const bf16* Ab = A + (size_t)m0 * K;
    const bf16* Bb = Bt + (size_t)n0 * K;
    const int srow = lane >> 2, scol = (lane & 3) * 8;
    floatx4 acc[4][4] = {};
    for (int k0 = 0; k0 < K; k0 += 32) {
        __syncthreads();
#pragma unroll
        for (int i = 0; i < 2; i++) {
            int ch = w * 2 + i;
            gl_lds16(Ab + (size_t)(ch * 16 + srow) * K + k0 + scol, As + ch * 512);
            gl_lds16(Bb + (size_t)(ch * 16 + srow) * K + k0 + scol, Bs + ch * 512);
        }
        __syncthreads();
        bf16x8 af[4], bfr[4];
#pragma unroll
        for (int mt = 0; mt < 4; mt++) af[mt] = *(const bf16x8*)(As + (wr + mt * 16 + l16) * 32 + quad * 8);
#pragma unroll
        for (int nt = 0; nt < 4; nt++) bfr[nt] = *(const bf16x8*)(Bs + (wc + nt * 16 + l16) * 32 + quad * 8);
#pragma unroll
        for (int mt = 0; mt < 4; mt++)
#pragma unroll
            for (int nt = 0; nt < 4; nt++)
                acc[mt][nt] = __builtin_amdgcn_mfma_f32_16x16x32_bf16(af[mt], bfr[nt], acc[mt][nt], 0, 0, 0);
    }
#pragma unroll
    for (int mt = 0; mt < 4; mt++)
#pragma unroll
        for (int nt = 0; nt < 4; nt++)
#pragma unroll
            for (int r = 0; r < 4; r++) {
                int row = m0 + wr + mt * 16 + quad * 4 + r;
                int col = n0 + wc + nt * 16 + l16;
                C[(size_t)row * N + col] = (OutT)acc[mt][nt][r];
            }
}

// ---------------- RoPE + scatter to Q,K (b,h,t,d) and V^T (b,h,d,t) ----------------
__global__ __launch_bounds__(256) void k_rope_scatter(const bf16* __restrict__ qkv,
                                                      const float* __restrict__ cosp, const float* __restrict__ sinp,
                                                      bf16* __restrict__ Qg, bf16* __restrict__ Kg, bf16* __restrict__ VTg) {
    __shared__ bf16 vt[128][66];
    int blk = blockIdx.x;
    int tb = blk & 31, h = (blk >> 5) & 15, b = blk >> 9;
    int t0 = tb * 64;
    int tid = threadIdx.x;
    int i = tid & 63, rr = tid >> 6;
#pragma unroll
    for (int it = 0; it < 16; it++) {
        int r = it * 4 + rr;
        int t = t0 + r;
        float c = cosp[t * 64 + i], s = sinp[t * 64 + i];
        size_t qbase = (size_t)(b * T_ + t) * D3_ + h * HD_;
        size_t obase = ((size_t)(b * H_ + h) * T_ + t) * HD_ + 2 * i;
        float x1 = (float)qkv[qbase + i], x2 = (float)qkv[qbase + 64 + i];
        bf16x2 qo = { (bf16)(x1 * c - x2 * s), (bf16)(x1 * s + x2 * c) };
        *(bf16x2*)(Qg + obase) = qo;
        x1 = (float)qkv[qbase + D_ + i]; x2 = (float)qkv[qbase + D_ + 64 + i];
        bf16x2 ko = { (bf16)(x1 * c - x2 * s), (bf16)(x1 * s + x2 * c) };
        *(bf16x2*)(Kg + obase) = ko;
    }
    // V transpose via LDS
#pragma unroll
    for (int it = 0; it < 32; it++) {
        int idx = it * 256 + tid;
        int r = idx >> 7, d = idx & 127;
        vt[d][r] = qkv[(size_t)(b * T_ + t0 + r) * D3_ + 2 * D_ + h * HD_ + d];
    }
    __syncthreads();
#pragma unroll
    for (int it = 0; it < 32; it++) {
        int idx = it * 256 + tid;
        int d = idx >> 6, tt = idx & 63;
        VTg[((size_t)(b * H_ + h) * HD_ + d) * T_ + t0 + tt] = vt[d][tt];
    }
}

// ---------------- Flash attention (causal, online softmax) ----------------
// grid: (B*H, T/128). block 256 = 4 waves; wave owns 32 Q rows.
__global__ __launch_bounds__(256, 2) void k_flash(const bf16* __restrict__ Qg, const bf16* __restrict__ Kg,
                                                  const bf16* __restrict__ VTg, bf16* __restrict__ Og) {
    __shared__ bf16 Ksh[64 * 128];      // K tile: 64 rows(t) x 128(d)
    __shared__ bf16 Vsh[128 * 64];      // V^T tile: 128 rows(d) x 64(t)
    __shared__ bf16 Psh[4 * 32 * 72];   // per-wave P staging, row stride 72 (pad)
    const int bh = blockIdx.x, qt = blockIdx.y;
    const int tid = threadIdx.x, w = tid >> 6, lane = tid & 63;
    const int quad = lane >> 4, l16 = lane & 15;
    const float scale = 0.08838834764831845f;  // 1/sqrt(128)
    const int wrow = w * 32;
    const bf16* Qb = Qg + ((size_t)bh * T_ + qt * 128) * HD_;
    bf16x8 qf[2][4];
#pragma unroll
    for (int mt = 0; mt < 2; mt++)
#pragma unroll
        for (int kc = 0; kc < 4; kc++)
            qf[mt][kc] = *(const bf16x8*)(Qb + (size_t)(wrow + mt * 16 + l16) * HD_ + kc * 32 + quad * 8);
    floatx4 oacc[2][8] = {};
    float mrow[2][4], lrow[2][4];
#pragma unroll
    for (int mt = 0; mt < 2; mt++)
#pragma unroll
        for (int r = 0; r < 4; r++) { mrow[mt][r] = -1e30f; lrow[mt][r] = 0.f; }
    bf16* Pw = Psh + w * 32 * 72;
    const int nkt = 2 * (qt + 1);
    for (int kt = 0; kt < nkt; kt++) {
        __syncthreads();   // previous tile's LDS reads done before restage
        const bf16* Kt = Kg + ((size_t)bh * T_ + kt * 64) * HD_;
        const bf16* Vt = VTg + (size_t)bh * HD_ * T_ + kt * 64;
#pragma unroll
        for (int i = 0; i < 4; i++) {
            int ch = w * 4 + i;
            gl_lds16(Kt + (size_t)(ch * 4 + (lane >> 4)) * HD_ + (lane & 15) * 8, Ksh + ch * 512);
            gl_lds16(Vt + (size_t)(ch * 8 + (lane >> 3)) * T_ + (lane & 7) * 8, Vsh + ch * 512);
        }
        __syncthreads();
        // S = Q K^T
        floatx4 s[2][4] = {};
#pragma unroll
        for (int kc = 0; kc < 4; kc++) {
            bf16x8 kf[4];
#pragma unroll
            for (int nt = 0; nt < 4; nt++)
                kf[nt] = *(const bf16x8*)(Ksh + (nt * 16 + l16) * 128 + kc * 32 + quad * 8);
#pragma unroll
            for (int mt = 0; mt < 2; mt++)
#pragma unroll
                for (int nt = 0; nt < 4; nt++)
                    s[mt][nt] = __builtin_amdgcn_mfma_f32_16x16x32_bf16(qf[mt][kc], kf[nt], s[mt][nt], 0, 0, 0);
        }
        // scale + causal mask (only the 2 diagonal tiles need it)
        const bool diag = (kt >= 2 * qt);
#pragma unroll
        for (int mt = 0; mt < 2; mt++)
#pragma unroll
            for (int nt = 0; nt < 4; nt++)
#pragma unroll
                for (int r = 0; r < 4; r++) {
                    float v = s[mt][nt][r] * scale;
                    if (diag) {
                        int gr = qt * 128 + wrow + mt * 16 + quad * 4 + r;
                        int gc = kt * 64 + nt * 16 + l16;
                        if (gc > gr) v = -1e30f;
                    }
                    s[mt][nt][r] = v;
                }
        // online softmax: row stats live in the 16 lanes of each quad (row = quad*4+r)
        float alpha[2][4];
#pragma unroll
        for (int mt = 0; mt < 2; mt++)
#pragma unroll
            for (int r = 0; r < 4; r++) {
                float mx = fmaxf(fmaxf(s[mt][0][r], s[mt][1][r]), fmaxf(s[mt][2][r], s[mt][3][r]));
                mx = fmaxf(mx, __shfl_xor(mx, 1));
                mx = fmaxf(mx, __shfl_xor(mx, 2));
                mx = fmaxf(mx, __shfl_xor(mx, 4));
                mx = fmaxf(mx, __shfl_xor(mx, 8));
                float mnew = fmaxf(mrow[mt][r], mx);
                alpha[mt][r] = __expf(mrow[mt][r] - mnew);
                mrow[mt][r] = mnew;
            }
#pragma unroll
        for (int mt = 0; mt < 2; mt++)
#pragma unroll
            for (int r = 0; r < 4; r++) {
                float rs = 0.f;
#pragma unroll
                for (int nt = 0; nt < 4; nt++) {
                    float p = __expf(s[mt][nt][r] - mrow[mt][r]);
                    s[mt][nt][r] = p;
                    rs += p;
                }
                rs += __shfl_xor(rs, 1); rs += __shfl_xor(rs, 2);
                rs += __shfl_xor(rs, 4); rs += __shfl_xor(rs, 8);
                lrow[mt][r] = lrow[mt][r] * alpha[mt][r] + rs;
            }
#pragma unroll
        for (int mt = 0; mt < 2; mt++)
#pragma unroll
            for (int nt2 = 0; nt2 < 8; nt2++)
#pragma unroll
                for (int r = 0; r < 4; r++)
                    oacc[mt][nt2][r] *= alpha[mt][r];
        // P (C-layout) -> LDS -> A-layout
#pragma unroll
        for (int mt = 0; mt < 2; mt++)
#pragma unroll
            for (int nt = 0; nt < 4; nt++)
#pragma unroll
                for (int r = 0; r < 4; r++)
                    Pw[(mt * 16 + quad * 4 + r) * 72 + nt * 16 + l16] = (bf16)s[mt][nt][r];
        __syncthreads();
        // O += P V
#pragma unroll
        for (int kc2 = 0; kc2 < 2; kc2++) {
            bf16x8 pf[2];
#pragma unroll
            for (int mt = 0; mt < 2; mt++)
                pf[mt] = *(const bf16x8*)(Pw + (mt * 16 + l16) * 72 + kc2 * 32 + quad * 8);
#pragma unroll
            for (int nt2 = 0; nt2 < 8; nt2++) {
                bf16x8 vf = *(const bf16x8*)(Vsh + (nt2 * 16 + l16) * 64 + kc2 * 32 + quad * 8);
#pragma unroll
                for (int mt = 0; mt < 2; mt++)
                    oacc[mt][nt2] = __builtin_amdgcn_mfma_f32_16x16x32_bf16(pf[mt], vf, oacc[mt][nt2], 0, 0, 0);
            }
        }
    }
    // epilogue: O/l, write (b,t,h,d) bf16
    const int b = bh >> 4, h = bh & 15;
#pragma unroll
    for (int mt = 0; mt < 2; mt++) {
        float inv[4];
#pragma unroll
        for (int r = 0; r < 4; r++) inv[r] = 1.0f / lrow[mt][r];
#pragma unroll
        for (int nt2 = 0; nt2 < 8; nt2++)
#pragma unroll
            for (int r = 0; r < 4; r++) {
                int t = qt * 128 + wrow + mt * 16 + quad * 4 + r;
                int c = h * HD_ + nt2 * 16 + l16;
                Og[(size_t)(b * T_ + t) * D_ + c] = (bf16)(oacc[mt][nt2][r] * inv[r]);
            }
    }
}

extern "C" void kernel_launch(void* const* d_in, const int* in_sizes, int n_in,
                              void* d_out, int out_size, void* d_ws, size_t ws_size,
                              hipStream_t stream) {
    const float* x     = (const float*)d_in[0];
    const float* cosp  = (const float*)d_in[1];
    const float* sinp  = (const float*)d_in[2];
    const float* Wqkv  = (const float*)d_in[3];
    const float* Wproj = (const float*)d_in[4];
    float* out = (float*)d_out;
    char* ws = (char*)d_ws;
    // workspace layout (144 MB total)
    bf16* xb     = (bf16*)(ws);                          // 16 MB (reused as O after GEMM1)
    bf16* WqkvT  = (bf16*)(ws + (size_t)(16u  << 20));   // 24 MB
    bf16* WprojT = (bf16*)(ws + (size_t)(40u  << 20));   //  8 MB
    bf16* qkv    = (bf16*)(ws + (size_t)(48u  << 20));   // 48 MB
    bf16* Qg     = (bf16*)(ws + (size_t)(96u  << 20));   // 16 MB
    bf16* Kg     = (bf16*)(ws + (size_t)(112u << 20));   // 16 MB
    bf16* VTg    = (bf16*)(ws + (size_t)(128u << 20));   // 16 MB
    bf16* Og     = xb;

    k_cvt<<<dim3(NT_ * D_ / 4 / 256), 256, 0, stream>>>(x, xb, NT_ * D_ / 4);
    k_tcvt<<<dim3(D3_ / 64, D_ / 64), 256, 0, stream>>>(Wqkv, WqkvT, D_, D3_);
    k_tcvt<<<dim3(D_ / 64, D_ / 64), 256, 0, stream>>>(Wproj, WprojT, D_, D_);
    k_gemm_bt<bf16><<<dim3(D3_ / 128, NT_ / 128), 256, 0, stream>>>(xb, WqkvT, qkv, NT_, D3_, D_);
    k_rope_scatter<<<dim3(B_ * H_ * T_ / 64), 256, 0, stream>>>(qkv, cosp, sinp, Qg, Kg, VTg);
    k_flash<<<dim3(B_ * H_, T_ / 128), 256, 0, stream>>>(Qg, Kg, VTg, Og);
    k_gemm_bt<float><<<dim3(D_ / 128, NT_ / 128), 256, 0, stream>>>(Og, WprojT, out, NT_, D_, D_);
}